// Round 1
// baseline (358.414 us; speedup 1.0000x reference)
//
#include <hip/hip_runtime.h>
#include <math.h>

#define NB 4
#define NN 512

// ---------------- kA: ha = X@Wa + b1, hb = X@Wb ; zero ru ----------------
__global__ void kA(const float* __restrict__ X, const float* __restrict__ W1,
                   const float* __restrict__ b1, float* __restrict__ ha,
                   float* __restrict__ hb, float* __restrict__ ru) {
  int b = blockIdx.y, n0 = blockIdx.x * 8;
  __shared__ float xs[8][128];
  int t = threadIdx.x;  // 128 threads
  for (int q = t; q < 1024; q += 128) {
    int r = q >> 7, f = q & 127;
    xs[r][f] = X[(size_t)(b * NN + n0 + r) * 128 + f];
  }
  int flat = b * 64 + blockIdx.x;
  if (flat < 16) ru[flat * 128 + t] = 0.f;
  __syncthreads();
  float accA[8] = {0,0,0,0,0,0,0,0}, accB[8] = {0,0,0,0,0,0,0,0};
  for (int f = 0; f < 128; ++f) {
    float wa = W1[f * 128 + t];
    float wb = W1[(128 + f) * 128 + t];
#pragma unroll
    for (int r = 0; r < 8; ++r) {
      accA[r] = fmaf(xs[r][f], wa, accA[r]);
      accB[r] = fmaf(xs[r][f], wb, accB[r]);
    }
  }
  float b1v = b1[t];
#pragma unroll
  for (int r = 0; r < 8; ++r) {
    ha[(size_t)(b * NN + n0 + r) * 128 + t] = accA[r] + b1v;
    hb[(size_t)(b * NN + n0 + r) * 128 + t] = accB[r];
  }
}

// ------- kB: K = exp(-5*cost), cost = relu(ha_i+hb_j+dist*wd)@W2 + b2 ----
// also accumulates row sums of K into ru (first Sinkhorn row half-iter)
__global__ void kB(const float* __restrict__ ha, const float* __restrict__ hb,
                   const float* __restrict__ coords, const float* __restrict__ W1,
                   const float* __restrict__ W2, const float* __restrict__ b2,
                   float* __restrict__ Km, float* __restrict__ ru) {
  int b = blockIdx.z, i0 = blockIdx.y * 32, j0 = blockIdx.x * 32;
  __shared__ alignas(16) float As[32][132];
  __shared__ alignas(16) float Bs[32][132];
  __shared__ alignas(16) float wd[128];
  __shared__ alignas(16) float w2[128];
  __shared__ float ci[32][3], cj[32][3];
  int t = threadIdx.x;  // 256
  for (int q = t; q < 1024; q += 256) {
    int r = q >> 5, c = (q & 31) * 4;
    *(float4*)&As[r][c] = *(const float4*)&ha[(size_t)(b * NN + i0 + r) * 128 + c];
    *(float4*)&Bs[r][c] = *(const float4*)&hb[(size_t)(b * NN + j0 + r) * 128 + c];
  }
  if (t < 128) { wd[t] = W1[256 * 128 + t]; w2[t] = W2[t]; }
  if (t < 96) ((float*)ci)[t] = coords[(size_t)(b * NN + i0) * 3 + t];
  else if (t < 192) ((float*)cj)[t - 96] = coords[(size_t)(b * NN + j0) * 3 + (t - 96)];
  __syncthreads();
  int tx = t & 15, ty = t >> 4;
  int ia = 2 * ty, ib = ia + 1, ja = tx, jb = tx + 16;
  float d00, d01, d10, d11;
  {
    float ax = ci[ia][0], ay = ci[ia][1], az = ci[ia][2];
    float bx = ci[ib][0], by = ci[ib][1], bz = ci[ib][2];
    float cx0 = cj[ja][0], cy0 = cj[ja][1], cz0 = cj[ja][2];
    float cx1 = cj[jb][0], cy1 = cj[jb][1], cz1 = cj[jb][2];
    float dx, dy, dz;
    dx = ax - cx0; dy = ay - cy0; dz = az - cz0;
    d00 = sqrtf(fmaxf(dx * dx + dy * dy + dz * dz, 0.f));
    dx = ax - cx1; dy = ay - cy1; dz = az - cz1;
    d01 = sqrtf(fmaxf(dx * dx + dy * dy + dz * dz, 0.f));
    dx = bx - cx0; dy = by - cy0; dz = bz - cz0;
    d10 = sqrtf(fmaxf(dx * dx + dy * dy + dz * dz, 0.f));
    dx = bx - cx1; dy = by - cy1; dz = bz - cz1;
    d11 = sqrtf(fmaxf(dx * dx + dy * dy + dz * dz, 0.f));
  }
  float a00 = 0, a01 = 0, a10 = 0, a11 = 0;
  for (int k = 0; k < 128; k += 4) {
    float4 A0 = *(float4*)&As[ia][k];
    float4 A1 = *(float4*)&As[ib][k];
    float4 B0 = *(float4*)&Bs[ja][k];
    float4 B1 = *(float4*)&Bs[jb][k];
    float4 W = *(float4*)&wd[k];
    float4 V = *(float4*)&w2[k];
#pragma unroll
    for (int kk = 0; kk < 4; ++kk) {
      float av = ((float*)&A0)[kk], av1 = ((float*)&A1)[kk];
      float bv = ((float*)&B0)[kk], bv1 = ((float*)&B1)[kk];
      float wv = ((float*)&W)[kk], vv = ((float*)&V)[kk];
      float t00 = fmaxf(fmaf(d00, wv, av + bv), 0.f);
      float t01 = fmaxf(fmaf(d01, wv, av + bv1), 0.f);
      float t10 = fmaxf(fmaf(d10, wv, av1 + bv), 0.f);
      float t11 = fmaxf(fmaf(d11, wv, av1 + bv1), 0.f);
      a00 = fmaf(t00, vv, a00);
      a01 = fmaf(t01, vv, a01);
      a10 = fmaf(t10, vv, a10);
      a11 = fmaf(t11, vv, a11);
    }
  }
  float b2v = b2[0];
  float k00 = __expf(-5.0f * (a00 + b2v));
  float k01 = __expf(-5.0f * (a01 + b2v));
  float k10 = __expf(-5.0f * (a10 + b2v));
  float k11 = __expf(-5.0f * (a11 + b2v));
  size_t r0 = (size_t)(b * NN + i0 + ia) * NN + j0;
  size_t r1 = (size_t)(b * NN + i0 + ib) * NN + j0;
  Km[r0 + ja] = k00; Km[r0 + jb] = k01;
  Km[r1 + ja] = k10; Km[r1 + jb] = k11;
  float s0 = k00 + k01, s1 = k10 + k11;
#pragma unroll
  for (int off = 1; off < 16; off <<= 1) {
    s0 += __shfl_xor(s0, off);
    s1 += __shfl_xor(s1, off);
  }
  if (tx == 0) {
    atomicAdd(&ru[b * NN + i0 + ia], s0);
    atomicAdd(&ru[b * NN + i0 + ib], s1);
  }
}

// ------- kCcol: rvp[ic] = partial col sums of K * (1/ru) -----------------
__global__ void kCcol(const float* __restrict__ Km, const float* __restrict__ ru,
                      float* __restrict__ rvp) {
  int ic = blockIdx.x, jc = blockIdx.y, b = blockIdx.z;
  __shared__ float uinv[64];
  int t = threadIdx.x;  // 256
  if (t < 64) uinv[t] = 1.0f / ru[b * NN + ic * 64 + t];
  __syncthreads();
  int j = jc * 256 + t;
  const float* Kp = Km + (size_t)(b * NN + ic * 64) * NN + j;
  float acc = 0.f;
#pragma unroll 8
  for (int ii = 0; ii < 64; ++ii) acc = fmaf(Kp[(size_t)ii * NN], uinv[ii], acc);
  rvp[ic * 2048 + b * NN + j] = acc;
}

// ------- kCrow: ru = row sums of K * (1/rv), rv = sum of rvp partials ----
__global__ void kCrow(const float* __restrict__ Km, const float* __restrict__ rvp,
                      float* __restrict__ ru) {
  int rc = blockIdx.x, b = blockIdx.y;
  __shared__ float vinv[512];
  int t = threadIdx.x;  // 256
  for (int j = t; j < 512; j += 256) {
    float s = 0.f;
#pragma unroll
    for (int ic = 0; ic < 8; ++ic) s += rvp[ic * 2048 + b * NN + j];
    vinv[j] = 1.0f / s;
  }
  __syncthreads();
  int w = t >> 6, l = t & 63;
  for (int m = 0; m < 16; ++m) {
    int r = rc * 64 + w * 16 + m;
    const float* Kp = Km + (size_t)(b * NN + r) * NN;
    float acc = 0.f;
#pragma unroll
    for (int mm = 0; mm < 8; ++mm) acc = fmaf(Kp[l + 64 * mm], vinv[l + 64 * mm], acc);
#pragma unroll
    for (int off = 1; off < 64; off <<= 1) acc += __shfl_xor(acc, off);
    if (l == 0) ru[b * NN + r] = acc;
  }
}

// ------- kAdj: adj = (1/ru_i) * K * (1/rv_j) -----------------------------
__global__ void kAdj(const float* __restrict__ Km, const float* __restrict__ ru,
                     const float* __restrict__ rvp, float* __restrict__ out) {
  int rc = blockIdx.x, b = blockIdx.y;
  __shared__ float vinv[512];
  __shared__ float uinv[64];
  int t = threadIdx.x;  // 256
  for (int j = t; j < 512; j += 256) {
    float s = 0.f;
#pragma unroll
    for (int ic = 0; ic < 8; ++ic) s += rvp[ic * 2048 + b * NN + j];
    vinv[j] = 1.0f / s;
  }
  if (t < 64) uinv[t] = 1.0f / ru[b * NN + rc * 64 + t];
  __syncthreads();
  for (int m = 0; m < 64; ++m) {
    int r = rc * 64 + m;
    float u = uinv[m];
    const float* Kp = Km + (size_t)(b * NN + r) * NN;
    float* op = out + (size_t)(b * NN + r) * NN;
    for (int j = t; j < 512; j += 256) op[j] = Kp[j] * u * vinv[j];
  }
}

// ------- kG1: xw = x @ Wg[l]  (2048x512, K=128) ---------------------------
__global__ void kG1(const float* __restrict__ x, const float* __restrict__ Wg,
                    float* __restrict__ xw) {
  int b = blockIdx.y, n0 = blockIdx.x * 8;
  __shared__ float xs[8][128];
  int t = threadIdx.x;  // 256
  for (int q = t; q < 1024; q += 256) {
    int r = q >> 7, f = q & 127;
    xs[r][f] = x[(size_t)(b * NN + n0 + r) * 128 + f];
  }
  __syncthreads();
  int c0 = t, c1 = t + 256;
  float acc0[8] = {0,0,0,0,0,0,0,0}, acc1[8] = {0,0,0,0,0,0,0,0};
  for (int f = 0; f < 128; ++f) {
    float w0 = Wg[f * 512 + c0], w1 = Wg[f * 512 + c1];
#pragma unroll
    for (int r = 0; r < 8; ++r) {
      float xv = xs[r][f];
      acc0[r] = fmaf(xv, w0, acc0[r]);
      acc1[r] = fmaf(xv, w1, acc1[r]);
    }
  }
#pragma unroll
  for (int r = 0; r < 8; ++r) {
    xw[(size_t)(b * NN + n0 + r) * 512 + c0] = acc0[r];
    xw[(size_t)(b * NN + n0 + r) * 512 + c1] = acc1[r];
  }
}

// ------- kG1b: s_src/s_dst (transposed layout [b*4+h][n]) ----------------
__global__ void kG1b(const float* __restrict__ xw, const float* __restrict__ asrc,
                     const float* __restrict__ adst, float* __restrict__ ssT,
                     float* __restrict__ sdT) {
  int n = blockIdx.x, b = blockIdx.y;
  int t = threadIdx.x;  // 128
  const float* row = xw + (size_t)(b * NN + n) * 512;
  float ps[4], pd[4];
#pragma unroll
  for (int q = 0; q < 4; ++q) {
    int c = q * 128 + t;
    float v = row[c];
    ps[q] = v * asrc[c];
    pd[q] = v * adst[c];
  }
#pragma unroll
  for (int off = 1; off < 64; off <<= 1) {
#pragma unroll
    for (int q = 0; q < 4; ++q) {
      ps[q] += __shfl_xor(ps[q], off);
      pd[q] += __shfl_xor(pd[q], off);
    }
  }
  __shared__ float part[2][8];
  int w = t >> 6, l = t & 63;
  if (l == 0) {
#pragma unroll
    for (int q = 0; q < 4; ++q) { part[w][q] = ps[q]; part[w][4 + q] = pd[q]; }
  }
  __syncthreads();
  if (t < 8) {
    float s = part[0][t] + part[1][t];
    int h = t & 3;
    if (t < 4) ssT[(size_t)(b * 4 + h) * 512 + n] = s;
    else       sdT[(size_t)(b * 4 + h) * 512 + n] = s;
  }
}

// ------- kG2: per (b, 8-row tile): softmax over j (rank-1 logits) + PV ---
__global__ __launch_bounds__(512) void kG2(const float* __restrict__ xw,
                                           const float* __restrict__ ssT,
                                           const float* __restrict__ sdT,
                                           const float* __restrict__ bg,
                                           float* __restrict__ xout) {
  int b = blockIdx.y, i0 = blockIdx.x * 8;
  __shared__ float ss[512];
  __shared__ float p[8][520];
  __shared__ float sd[8];
  __shared__ alignas(16) float scratch[8][32][2][4];
  int t = threadIdx.x;  // 512
  int fq = t & 31, r = (t >> 5) & 7, jh = t >> 8;
  int wv = t >> 6, l = t & 63;
  float acc0 = 0, acc1 = 0, acc2 = 0, acc3 = 0;
  for (int h = 0; h < 4; ++h) {
    ss[t & 511] = ssT[(size_t)(b * 4 + h) * 512 + (t & 511)];
    if (t < 8) sd[t] = sdT[(size_t)(b * 4 + h) * 512 + i0 + t];
    __syncthreads();
    // softmax: wave wv owns row wv
    float sdr = sd[wv];
    float ev[8];
    float mx = -1e30f;
#pragma unroll
    for (int mm = 0; mm < 8; ++mm) {
      float e = sdr + ss[l + 64 * mm];
      e = (e >= 0.f) ? e : 0.2f * e;
      ev[mm] = e;
      mx = fmaxf(mx, e);
    }
#pragma unroll
    for (int off = 1; off < 64; off <<= 1) mx = fmaxf(mx, __shfl_xor(mx, off));
    float sum = 0.f;
#pragma unroll
    for (int mm = 0; mm < 8; ++mm) {
      float pe = __expf(ev[mm] - mx);
      p[wv][l + 64 * mm] = pe;
      sum += pe;
    }
#pragma unroll
    for (int off = 1; off < 64; off <<= 1) sum += __shfl_xor(sum, off);
    float sc = 1.0f / (4.0f * sum);
#pragma unroll
    for (int mm = 0; mm < 8; ++mm) p[wv][l + 64 * mm] *= sc;
    __syncthreads();
    // weighted sum: thread = (jh, r, fq): acc[f] += p[r][j] * xw[b,j,h,f]
    const float* xwb = xw + (size_t)(b * NN) * 512 + h * 128 + fq * 4;
    for (int m2 = 0; m2 < 256; ++m2) {
      int j = jh + 2 * m2;
      float4 xv = *(const float4*)&xwb[(size_t)j * 512];
      float pv = p[r][j];
      acc0 = fmaf(pv, xv.x, acc0);
      acc1 = fmaf(pv, xv.y, acc1);
      acc2 = fmaf(pv, xv.z, acc2);
      acc3 = fmaf(pv, xv.w, acc3);
    }
    __syncthreads();
  }
  scratch[r][fq][jh][0] = acc0;
  scratch[r][fq][jh][1] = acc1;
  scratch[r][fq][jh][2] = acc2;
  scratch[r][fq][jh][3] = acc3;
  __syncthreads();
  if (jh == 0) {
    float o0 = scratch[r][fq][0][0] + scratch[r][fq][1][0] + bg[fq * 4 + 0];
    float o1 = scratch[r][fq][0][1] + scratch[r][fq][1][1] + bg[fq * 4 + 1];
    float o2 = scratch[r][fq][0][2] + scratch[r][fq][1][2] + bg[fq * 4 + 2];
    float o3 = scratch[r][fq][0][3] + scratch[r][fq][1][3] + bg[fq * 4 + 3];
    float4 o = make_float4(o0, o1, o2, o3);
    *(float4*)&xout[(size_t)(b * NN + i0 + r) * 128 + fq * 4] = o;
  }
}

// ------- kF: final_adj = sigmoid(x @ x^T) --------------------------------
__global__ void kF(const float* __restrict__ x, float* __restrict__ out) {
  int b = blockIdx.z, i0 = blockIdx.y * 32, j0 = blockIdx.x * 32;
  __shared__ alignas(16) float As[32][132];
  __shared__ alignas(16) float Bs[32][132];
  int t = threadIdx.x;  // 256
  for (int q = t; q < 1024; q += 256) {
    int r = q >> 5, c = (q & 31) * 4;
    *(float4*)&As[r][c] = *(const float4*)&x[(size_t)(b * NN + i0 + r) * 128 + c];
    *(float4*)&Bs[r][c] = *(const float4*)&x[(size_t)(b * NN + j0 + r) * 128 + c];
  }
  __syncthreads();
  int tx = t & 15, ty = t >> 4;
  int ia = 2 * ty, ib = ia + 1, ja = tx, jb = tx + 16;
  float a00 = 0, a01 = 0, a10 = 0, a11 = 0;
  for (int k = 0; k < 128; k += 4) {
    float4 A0 = *(float4*)&As[ia][k];
    float4 A1 = *(float4*)&As[ib][k];
    float4 B0 = *(float4*)&Bs[ja][k];
    float4 B1 = *(float4*)&Bs[jb][k];
#pragma unroll
    for (int kk = 0; kk < 4; ++kk) {
      float av = ((float*)&A0)[kk], av1 = ((float*)&A1)[kk];
      float bv = ((float*)&B0)[kk], bv1 = ((float*)&B1)[kk];
      a00 = fmaf(av, bv, a00);
      a01 = fmaf(av, bv1, a01);
      a10 = fmaf(av1, bv, a10);
      a11 = fmaf(av1, bv1, a11);
    }
  }
  size_t r0 = (size_t)(b * NN + i0 + ia) * NN + j0;
  size_t r1 = (size_t)(b * NN + i0 + ib) * NN + j0;
  out[r0 + ja] = 1.0f / (1.0f + __expf(-a00));
  out[r0 + jb] = 1.0f / (1.0f + __expf(-a01));
  out[r1 + ja] = 1.0f / (1.0f + __expf(-a10));
  out[r1 + jb] = 1.0f / (1.0f + __expf(-a11));
}

extern "C" void kernel_launch(void* const* d_in, const int* in_sizes, int n_in,
                              void* d_out, int out_size, void* d_ws, size_t ws_size,
                              hipStream_t stream) {
  (void)in_sizes; (void)n_in; (void)out_size; (void)ws_size;
  const float* X   = (const float*)d_in[0];
  const float* C   = (const float*)d_in[1];
  const float* W1  = (const float*)d_in[2];
  const float* b1  = (const float*)d_in[3];
  const float* W2  = (const float*)d_in[4];
  const float* b2  = (const float*)d_in[5];
  const float* Wg  = (const float*)d_in[6];
  const float* as_ = (const float*)d_in[7];
  const float* ad_ = (const float*)d_in[8];
  const float* bg  = (const float*)d_in[9];
  float* out = (float*)d_out;
  float* ws = (float*)d_ws;

  float* ha  = ws;                 // 262144
  float* hb  = ws + 262144;        // 262144
  float* Km  = ws + 524288;        // 1048576
  float* ru  = ws + 1572864;       // 2048
  float* rvp = ws + 1574912;       // 16384 (8 x 2048)
  float* xw  = ws + 1591296;       // 1048576
  float* ssT = ws + 2639872;       // 8192
  float* sdT = ws + 2648064;       // 8192
  float* x1  = ws + 2656256;       // 262144
  float* x2  = ws + 2918400;       // 262144

  kA<<<dim3(64, 4), 128, 0, stream>>>(X, W1, b1, ha, hb, ru);
  kB<<<dim3(16, 16, 4), 256, 0, stream>>>(ha, hb, C, W1, W2, b2, Km, ru);
  // Sinkhorn: u_t = 1/(K v_{t-1}), v_t = 1/(K^T u_t); kB produced ru for u_1
  kCcol<<<dim3(8, 2, 4), 256, 0, stream>>>(Km, ru, rvp);
  for (int it = 0; it < 9; ++it) {
    kCrow<<<dim3(8, 4), 256, 0, stream>>>(Km, rvp, ru);
    kCcol<<<dim3(8, 2, 4), 256, 0, stream>>>(Km, ru, rvp);
  }
  kAdj<<<dim3(8, 4), 256, 0, stream>>>(Km, ru, rvp, out + 1048576);
  // GAT layer 0
  kG1<<<dim3(64, 4), 256, 0, stream>>>(X, Wg, xw);
  kG1b<<<dim3(512, 4), 128, 0, stream>>>(xw, as_, ad_, ssT, sdT);
  kG2<<<dim3(64, 4), 512, 0, stream>>>(xw, ssT, sdT, bg, x1);
  // GAT layer 1
  kG1<<<dim3(64, 4), 256, 0, stream>>>(x1, Wg + 65536, xw);
  kG1b<<<dim3(512, 4), 128, 0, stream>>>(xw, as_ + 512, ad_ + 512, ssT, sdT);
  kG2<<<dim3(64, 4), 512, 0, stream>>>(xw, ssT, sdT, bg + 128, x2);
  // final adjacency
  kF<<<dim3(16, 16, 4), 256, 0, stream>>>(x2, out);
}

// Round 2
// 319.617 us; speedup vs baseline: 1.1214x; 1.1214x over previous
//
#include <hip/hip_runtime.h>
#include <math.h>

#define NB 4
#define NN 512

// ---------------- kA: ha = X@Wa + b1, hb = X@Wb ; zero ru ----------------
__global__ void kA(const float* __restrict__ X, const float* __restrict__ W1,
                   const float* __restrict__ b1, float* __restrict__ ha,
                   float* __restrict__ hb, float* __restrict__ ru) {
  int b = blockIdx.y, n0 = blockIdx.x * 8;
  __shared__ float xs[8][128];
  int t = threadIdx.x;  // 128 threads
  for (int q = t; q < 1024; q += 128) {
    int r = q >> 7, f = q & 127;
    xs[r][f] = X[(size_t)(b * NN + n0 + r) * 128 + f];
  }
  int flat = b * 64 + blockIdx.x;
  if (flat < 16) ru[flat * 128 + t] = 0.f;
  __syncthreads();
  float accA[8] = {0,0,0,0,0,0,0,0}, accB[8] = {0,0,0,0,0,0,0,0};
  for (int f = 0; f < 128; ++f) {
    float wa = W1[f * 128 + t];
    float wb = W1[(128 + f) * 128 + t];
#pragma unroll
    for (int r = 0; r < 8; ++r) {
      accA[r] = fmaf(xs[r][f], wa, accA[r]);
      accB[r] = fmaf(xs[r][f], wb, accB[r]);
    }
  }
  float b1v = b1[t];
#pragma unroll
  for (int r = 0; r < 8; ++r) {
    ha[(size_t)(b * NN + n0 + r) * 128 + t] = accA[r] + b1v;
    hb[(size_t)(b * NN + n0 + r) * 128 + t] = accB[r];
  }
}

// ------- kB: K = exp(-5*cost), cost = relu(ha_i+hb_j+dist*wd)@W2 + b2 ----
// also accumulates row sums of K into ru (first Sinkhorn row half-iter)
__global__ void kB(const float* __restrict__ ha, const float* __restrict__ hb,
                   const float* __restrict__ coords, const float* __restrict__ W1,
                   const float* __restrict__ W2, const float* __restrict__ b2,
                   float* __restrict__ Km, float* __restrict__ ru) {
  int b = blockIdx.z, i0 = blockIdx.y * 32, j0 = blockIdx.x * 32;
  __shared__ alignas(16) float As[32][132];
  __shared__ alignas(16) float Bs[32][132];
  __shared__ alignas(16) float wd[128];
  __shared__ alignas(16) float w2[128];
  __shared__ float ci[32][3], cj[32][3];
  int t = threadIdx.x;  // 256
  for (int q = t; q < 1024; q += 256) {
    int r = q >> 5, c = (q & 31) * 4;
    *(float4*)&As[r][c] = *(const float4*)&ha[(size_t)(b * NN + i0 + r) * 128 + c];
    *(float4*)&Bs[r][c] = *(const float4*)&hb[(size_t)(b * NN + j0 + r) * 128 + c];
  }
  if (t < 128) { wd[t] = W1[256 * 128 + t]; w2[t] = W2[t]; }
  if (t < 96) ((float*)ci)[t] = coords[(size_t)(b * NN + i0) * 3 + t];
  else if (t < 192) ((float*)cj)[t - 96] = coords[(size_t)(b * NN + j0) * 3 + (t - 96)];
  __syncthreads();
  int tx = t & 15, ty = t >> 4;
  int ia = 2 * ty, ib = ia + 1, ja = tx, jb = tx + 16;
  float d00, d01, d10, d11;
  {
    float ax = ci[ia][0], ay = ci[ia][1], az = ci[ia][2];
    float bx = ci[ib][0], by = ci[ib][1], bz = ci[ib][2];
    float cx0 = cj[ja][0], cy0 = cj[ja][1], cz0 = cj[ja][2];
    float cx1 = cj[jb][0], cy1 = cj[jb][1], cz1 = cj[jb][2];
    float dx, dy, dz;
    dx = ax - cx0; dy = ay - cy0; dz = az - cz0;
    d00 = sqrtf(fmaxf(dx * dx + dy * dy + dz * dz, 0.f));
    dx = ax - cx1; dy = ay - cy1; dz = az - cz1;
    d01 = sqrtf(fmaxf(dx * dx + dy * dy + dz * dz, 0.f));
    dx = bx - cx0; dy = by - cy0; dz = bz - cz0;
    d10 = sqrtf(fmaxf(dx * dx + dy * dy + dz * dz, 0.f));
    dx = bx - cx1; dy = by - cy1; dz = bz - cz1;
    d11 = sqrtf(fmaxf(dx * dx + dy * dy + dz * dz, 0.f));
  }
  float a00 = 0, a01 = 0, a10 = 0, a11 = 0;
  for (int k = 0; k < 128; k += 4) {
    float4 A0 = *(float4*)&As[ia][k];
    float4 A1 = *(float4*)&As[ib][k];
    float4 B0 = *(float4*)&Bs[ja][k];
    float4 B1 = *(float4*)&Bs[jb][k];
    float4 W = *(float4*)&wd[k];
    float4 V = *(float4*)&w2[k];
#pragma unroll
    for (int kk = 0; kk < 4; ++kk) {
      float av = ((float*)&A0)[kk], av1 = ((float*)&A1)[kk];
      float bv = ((float*)&B0)[kk], bv1 = ((float*)&B1)[kk];
      float wv = ((float*)&W)[kk], vv = ((float*)&V)[kk];
      float t00 = fmaxf(fmaf(d00, wv, av + bv), 0.f);
      float t01 = fmaxf(fmaf(d01, wv, av + bv1), 0.f);
      float t10 = fmaxf(fmaf(d10, wv, av1 + bv), 0.f);
      float t11 = fmaxf(fmaf(d11, wv, av1 + bv1), 0.f);
      a00 = fmaf(t00, vv, a00);
      a01 = fmaf(t01, vv, a01);
      a10 = fmaf(t10, vv, a10);
      a11 = fmaf(t11, vv, a11);
    }
  }
  float b2v = b2[0];
  float k00 = __expf(-5.0f * (a00 + b2v));
  float k01 = __expf(-5.0f * (a01 + b2v));
  float k10 = __expf(-5.0f * (a10 + b2v));
  float k11 = __expf(-5.0f * (a11 + b2v));
  size_t r0 = (size_t)(b * NN + i0 + ia) * NN + j0;
  size_t r1 = (size_t)(b * NN + i0 + ib) * NN + j0;
  Km[r0 + ja] = k00; Km[r0 + jb] = k01;
  Km[r1 + ja] = k10; Km[r1 + jb] = k11;
  float s0 = k00 + k01, s1 = k10 + k11;
#pragma unroll
  for (int off = 1; off < 16; off <<= 1) {
    s0 += __shfl_xor(s0, off);
    s1 += __shfl_xor(s1, off);
  }
  if (tx == 0) {
    atomicAdd(&ru[b * NN + i0 + ia], s0);
    atomicAdd(&ru[b * NN + i0 + ib], s1);
  }
}

// ------- kCcol: rvp[ic] = partial col sums of K * (1/ru) -----------------
__global__ void kCcol(const float* __restrict__ Km, const float* __restrict__ ru,
                      float* __restrict__ rvp) {
  int ic = blockIdx.x, jc = blockIdx.y, b = blockIdx.z;
  __shared__ float uinv[64];
  int t = threadIdx.x;  // 256
  if (t < 64) uinv[t] = 1.0f / ru[b * NN + ic * 64 + t];
  __syncthreads();
  int j = jc * 256 + t;
  const float* Kp = Km + (size_t)(b * NN + ic * 64) * NN + j;
  float acc = 0.f;
#pragma unroll 8
  for (int ii = 0; ii < 64; ++ii) acc = fmaf(Kp[(size_t)ii * NN], uinv[ii], acc);
  rvp[ic * 2048 + b * NN + j] = acc;
}

// ------- kCrow: ru = row sums of K * (1/rv), rv = sum of rvp partials ----
__global__ void kCrow(const float* __restrict__ Km, const float* __restrict__ rvp,
                      float* __restrict__ ru) {
  int rc = blockIdx.x, b = blockIdx.y;
  __shared__ float vinv[512];
  int t = threadIdx.x;  // 256
  for (int j = t; j < 512; j += 256) {
    float s = 0.f;
#pragma unroll
    for (int ic = 0; ic < 8; ++ic) s += rvp[ic * 2048 + b * NN + j];
    vinv[j] = 1.0f / s;
  }
  __syncthreads();
  int w = t >> 6, l = t & 63;
  for (int m = 0; m < 16; ++m) {
    int r = rc * 64 + w * 16 + m;
    const float* Kp = Km + (size_t)(b * NN + r) * NN;
    float acc = 0.f;
#pragma unroll
    for (int mm = 0; mm < 8; ++mm) acc = fmaf(Kp[l + 64 * mm], vinv[l + 64 * mm], acc);
#pragma unroll
    for (int off = 1; off < 64; off <<= 1) acc += __shfl_xor(acc, off);
    if (l == 0) ru[b * NN + r] = acc;
  }
}

// ------- kAdj: adj = (1/ru_i) * K * (1/rv_j) -----------------------------
__global__ void kAdj(const float* __restrict__ Km, const float* __restrict__ ru,
                     const float* __restrict__ rvp, float* __restrict__ out) {
  int rc = blockIdx.x, b = blockIdx.y;
  __shared__ float vinv[512];
  __shared__ float uinv[64];
  int t = threadIdx.x;  // 256
  for (int j = t; j < 512; j += 256) {
    float s = 0.f;
#pragma unroll
    for (int ic = 0; ic < 8; ++ic) s += rvp[ic * 2048 + b * NN + j];
    vinv[j] = 1.0f / s;
  }
  if (t < 64) uinv[t] = 1.0f / ru[b * NN + rc * 64 + t];
  __syncthreads();
  for (int m = 0; m < 64; ++m) {
    int r = rc * 64 + m;
    float u = uinv[m];
    const float* Kp = Km + (size_t)(b * NN + r) * NN;
    float* op = out + (size_t)(b * NN + r) * NN;
    for (int j = t; j < 512; j += 256) op[j] = Kp[j] * u * vinv[j];
  }
}

// ------- kG1: xw = x @ Wg[l]  (2048x512, K=128) ---------------------------
__global__ void kG1(const float* __restrict__ x, const float* __restrict__ Wg,
                    float* __restrict__ xw) {
  int b = blockIdx.y, n0 = blockIdx.x * 8;
  __shared__ float xs[8][128];
  int t = threadIdx.x;  // 256
  for (int q = t; q < 1024; q += 256) {
    int r = q >> 7, f = q & 127;
    xs[r][f] = x[(size_t)(b * NN + n0 + r) * 128 + f];
  }
  __syncthreads();
  int c0 = t, c1 = t + 256;
  float acc0[8] = {0,0,0,0,0,0,0,0}, acc1[8] = {0,0,0,0,0,0,0,0};
  for (int f = 0; f < 128; ++f) {
    float w0 = Wg[f * 512 + c0], w1 = Wg[f * 512 + c1];
#pragma unroll
    for (int r = 0; r < 8; ++r) {
      float xv = xs[r][f];
      acc0[r] = fmaf(xv, w0, acc0[r]);
      acc1[r] = fmaf(xv, w1, acc1[r]);
    }
  }
#pragma unroll
  for (int r = 0; r < 8; ++r) {
    xw[(size_t)(b * NN + n0 + r) * 512 + c0] = acc0[r];
    xw[(size_t)(b * NN + n0 + r) * 512 + c1] = acc1[r];
  }
}

// ------- kG1b: s_src/s_dst (transposed layout [b*4+h][n]) ----------------
__global__ void kG1b(const float* __restrict__ xw, const float* __restrict__ asrc,
                     const float* __restrict__ adst, float* __restrict__ ssT,
                     float* __restrict__ sdT) {
  int n = blockIdx.x, b = blockIdx.y;
  int t = threadIdx.x;  // 128
  const float* row = xw + (size_t)(b * NN + n) * 512;
  float ps[4], pd[4];
#pragma unroll
  for (int q = 0; q < 4; ++q) {
    int c = q * 128 + t;
    float v = row[c];
    ps[q] = v * asrc[c];
    pd[q] = v * adst[c];
  }
#pragma unroll
  for (int off = 1; off < 64; off <<= 1) {
#pragma unroll
    for (int q = 0; q < 4; ++q) {
      ps[q] += __shfl_xor(ps[q], off);
      pd[q] += __shfl_xor(pd[q], off);
    }
  }
  __shared__ float part[2][8];
  int w = t >> 6, l = t & 63;
  if (l == 0) {
#pragma unroll
    for (int q = 0; q < 4; ++q) { part[w][q] = ps[q]; part[w][4 + q] = pd[q]; }
  }
  __syncthreads();
  if (t < 8) {
    float s = part[0][t] + part[1][t];
    int h = t & 3;
    if (t < 4) ssT[(size_t)(b * 4 + h) * 512 + n] = s;
    else       sdT[(size_t)(b * 4 + h) * 512 + n] = s;
  }
}

// ------- kSmax: ssmax[b*4+h] = max_n ssT[b*4+h][n] -----------------------
__global__ void kSmax(const float* __restrict__ ssT, float* __restrict__ ssmax) {
  int h = blockIdx.x, b = blockIdx.y;
  int t = threadIdx.x;  // 512
  float v = ssT[(size_t)(b * 4 + h) * 512 + t];
#pragma unroll
  for (int off = 1; off < 64; off <<= 1) v = fmaxf(v, __shfl_xor(v, off));
  __shared__ float wp[8];
  int w = t >> 6, l = t & 63;
  if (l == 0) wp[w] = v;
  __syncthreads();
  if (t == 0) {
    float m = wp[0];
#pragma unroll
    for (int q = 1; q < 8; ++q) m = fmaxf(m, wp[q]);
    ssmax[b * 4 + h] = m;
  }
}

// ------- kG2n: per (b,h,16-row tile): P tile in LDS + P @ XW_h -----------
// partial[(b*4+h)*512 + i][f] = sum_j softmax_p(i,j) * xw[b,j,h,f] / 4
#define PLD 517
__global__ __launch_bounds__(256) void kG2n(const float* __restrict__ xw,
                                            const float* __restrict__ ssT,
                                            const float* __restrict__ sdT,
                                            const float* __restrict__ ssmax,
                                            float* __restrict__ partial) {
  int b = blockIdx.z, h = blockIdx.y, i0 = blockIdx.x * 16;
  int bh = b * 4 + h;
  __shared__ float ss[512];
  __shared__ float pl[16][PLD];
  __shared__ float sdl[16], mxl[16], idl[16];
  int t = threadIdx.x;  // 256
  for (int q = t; q < 512; q += 256) ss[q] = ssT[(size_t)bh * 512 + q];
  if (t < 16) {
    float sdv = sdT[(size_t)bh * 512 + i0 + t];
    sdl[t] = sdv;
    float m = sdv + ssmax[bh];
    mxl[t] = (m >= 0.f) ? m : 0.2f * m;
  }
  __syncthreads();
  // phase A: thread (il = t>>4, jq = t&15) computes p[il][jq*32 .. +32)
  {
    int il = t >> 4, jq = t & 15;
    float mx = mxl[il], sdv = sdl[il];
    float den = 0.f;
#pragma unroll 8
    for (int jj = 0; jj < 32; ++jj) {
      int j = jq * 32 + jj;
      float e = sdv + ss[j];
      e = (e >= 0.f) ? e : 0.2f * e;
      float pe = __expf(e - mx);
      pl[il][j] = pe;
      den += pe;
    }
#pragma unroll
    for (int off = 1; off < 16; off <<= 1) den += __shfl_xor(den, off);
    if (jq == 0) idl[il] = 1.0f / (4.0f * den);
  }
  __syncthreads();
  // phase B: thread (r8 = t>>5 in 0..7, fq = t&31): rows r8, r8+8
  int r8 = t >> 5, fq = t & 31;
  const float* xp = xw + (size_t)(b * NN) * 512 + h * 128 + fq * 4;
  float4 a0 = {0,0,0,0}, a1 = {0,0,0,0};
#pragma unroll 4
  for (int j = 0; j < 512; ++j) {
    float4 xv = *(const float4*)&xp[(size_t)j * 512];
    float p0 = pl[r8][j], p1 = pl[r8 + 8][j];
    a0.x = fmaf(p0, xv.x, a0.x);
    a0.y = fmaf(p0, xv.y, a0.y);
    a0.z = fmaf(p0, xv.z, a0.z);
    a0.w = fmaf(p0, xv.w, a0.w);
    a1.x = fmaf(p1, xv.x, a1.x);
    a1.y = fmaf(p1, xv.y, a1.y);
    a1.z = fmaf(p1, xv.z, a1.z);
    a1.w = fmaf(p1, xv.w, a1.w);
  }
  float s0 = idl[r8], s1 = idl[r8 + 8];
  a0.x *= s0; a0.y *= s0; a0.z *= s0; a0.w *= s0;
  a1.x *= s1; a1.y *= s1; a1.z *= s1; a1.w *= s1;
  *(float4*)&partial[((size_t)bh * NN + i0 + r8) * 128 + fq * 4] = a0;
  *(float4*)&partial[((size_t)bh * NN + i0 + r8 + 8) * 128 + fq * 4] = a1;
}

// ------- kRed: xo[b,i,f] = sum_h partial[b,h,i,f] + bg[f] ----------------
__global__ void kRed(const float* __restrict__ partial, const float* __restrict__ bg,
                     float* __restrict__ xo) {
  int idx = blockIdx.x * 256 + threadIdx.x;  // float4 index, 65536 total
  int f4 = idx & 31;
  int rest = idx >> 5;           // b*512 + i
  int b = rest >> 9, i = rest & 511;
  const float* pp = partial + (((size_t)b * 4) * NN + i) * 128 + f4 * 4;
  float4 s = *(const float4*)pp;
  const float* p1 = pp + (size_t)NN * 128;
  const float* p2 = pp + (size_t)2 * NN * 128;
  const float* p3 = pp + (size_t)3 * NN * 128;
  float4 v1 = *(const float4*)p1, v2 = *(const float4*)p2, v3 = *(const float4*)p3;
  float4 bb = *(const float4*)&bg[f4 * 4];
  s.x += v1.x + v2.x + v3.x + bb.x;
  s.y += v1.y + v2.y + v3.y + bb.y;
  s.z += v1.z + v2.z + v3.z + bb.z;
  s.w += v1.w + v2.w + v3.w + bb.w;
  *(float4*)&xo[(size_t)rest * 128 + f4 * 4] = s;
}

// ------- kF: final_adj = sigmoid(x @ x^T) --------------------------------
__global__ void kF(const float* __restrict__ x, float* __restrict__ out) {
  int b = blockIdx.z, i0 = blockIdx.y * 32, j0 = blockIdx.x * 32;
  __shared__ alignas(16) float As[32][132];
  __shared__ alignas(16) float Bs[32][132];
  int t = threadIdx.x;  // 256
  for (int q = t; q < 1024; q += 256) {
    int r = q >> 5, c = (q & 31) * 4;
    *(float4*)&As[r][c] = *(const float4*)&x[(size_t)(b * NN + i0 + r) * 128 + c];
    *(float4*)&Bs[r][c] = *(const float4*)&x[(size_t)(b * NN + j0 + r) * 128 + c];
  }
  __syncthreads();
  int tx = t & 15, ty = t >> 4;
  int ia = 2 * ty, ib = ia + 1, ja = tx, jb = tx + 16;
  float a00 = 0, a01 = 0, a10 = 0, a11 = 0;
  for (int k = 0; k < 128; k += 4) {
    float4 A0 = *(float4*)&As[ia][k];
    float4 A1 = *(float4*)&As[ib][k];
    float4 B0 = *(float4*)&Bs[ja][k];
    float4 B1 = *(float4*)&Bs[jb][k];
#pragma unroll
    for (int kk = 0; kk < 4; ++kk) {
      float av = ((float*)&A0)[kk], av1 = ((float*)&A1)[kk];
      float bv = ((float*)&B0)[kk], bv1 = ((float*)&B1)[kk];
      a00 = fmaf(av, bv, a00);
      a01 = fmaf(av, bv1, a01);
      a10 = fmaf(av1, bv, a10);
      a11 = fmaf(av1, bv1, a11);
    }
  }
  size_t r0 = (size_t)(b * NN + i0 + ia) * NN + j0;
  size_t r1 = (size_t)(b * NN + i0 + ib) * NN + j0;
  out[r0 + ja] = 1.0f / (1.0f + __expf(-a00));
  out[r0 + jb] = 1.0f / (1.0f + __expf(-a01));
  out[r1 + ja] = 1.0f / (1.0f + __expf(-a10));
  out[r1 + jb] = 1.0f / (1.0f + __expf(-a11));
}

extern "C" void kernel_launch(void* const* d_in, const int* in_sizes, int n_in,
                              void* d_out, int out_size, void* d_ws, size_t ws_size,
                              hipStream_t stream) {
  (void)in_sizes; (void)n_in; (void)out_size; (void)ws_size;
  const float* X   = (const float*)d_in[0];
  const float* C   = (const float*)d_in[1];
  const float* W1  = (const float*)d_in[2];
  const float* b1  = (const float*)d_in[3];
  const float* W2  = (const float*)d_in[4];
  const float* b2  = (const float*)d_in[5];
  const float* Wg  = (const float*)d_in[6];
  const float* as_ = (const float*)d_in[7];
  const float* ad_ = (const float*)d_in[8];
  const float* bg  = (const float*)d_in[9];
  float* out = (float*)d_out;
  float* ws = (float*)d_ws;

  float* ha    = ws;                 // 262144
  float* hb    = ws + 262144;        // 262144
  float* Km    = ws + 524288;        // 1048576
  float* ru    = ws + 1572864;       // 2048
  float* rvp   = ws + 1574912;       // 16384 (8 x 2048)
  float* xw    = ws + 1591296;       // 1048576
  float* ssT   = ws + 2639872;       // 8192
  float* sdT   = ws + 2648064;       // 8192
  float* x1    = ws + 2656256;       // 262144
  float* x2    = ws + 2918400;       // 262144
  float* ssmax = ws + 3180544;       // 16
  float* partial = Km;               // alias: Km is dead after kAdj

  kA<<<dim3(64, 4), 128, 0, stream>>>(X, W1, b1, ha, hb, ru);
  kB<<<dim3(16, 16, 4), 256, 0, stream>>>(ha, hb, C, W1, W2, b2, Km, ru);
  // Sinkhorn: u_t = 1/(K v_{t-1}), v_t = 1/(K^T u_t); kB produced ru for u_1
  kCcol<<<dim3(8, 2, 4), 256, 0, stream>>>(Km, ru, rvp);
  for (int it = 0; it < 9; ++it) {
    kCrow<<<dim3(8, 4), 256, 0, stream>>>(Km, rvp, ru);
    kCcol<<<dim3(8, 2, 4), 256, 0, stream>>>(Km, ru, rvp);
  }
  kAdj<<<dim3(8, 4), 256, 0, stream>>>(Km, ru, rvp, out + 1048576);
  // GAT layer 0
  kG1<<<dim3(64, 4), 256, 0, stream>>>(X, Wg, xw);
  kG1b<<<dim3(512, 4), 128, 0, stream>>>(xw, as_, ad_, ssT, sdT);
  kSmax<<<dim3(4, 4), 512, 0, stream>>>(ssT, ssmax);
  kG2n<<<dim3(32, 4, 4), 256, 0, stream>>>(xw, ssT, sdT, ssmax, partial);
  kRed<<<256, 256, 0, stream>>>(partial, bg, x1);
  // GAT layer 1
  kG1<<<dim3(64, 4), 256, 0, stream>>>(x1, Wg + 65536, xw);
  kG1b<<<dim3(512, 4), 128, 0, stream>>>(xw, as_ + 512, ad_ + 512, ssT, sdT);
  kSmax<<<dim3(4, 4), 512, 0, stream>>>(ssT, ssmax);
  kG2n<<<dim3(32, 4, 4), 256, 0, stream>>>(xw, ssT, sdT, ssmax, partial);
  kRed<<<256, 256, 0, stream>>>(partial, bg + 128, x2);
  // final adjacency
  kF<<<dim3(16, 16, 4), 256, 0, stream>>>(x2, out);
}

// Round 3
// 308.154 us; speedup vs baseline: 1.1631x; 1.0372x over previous
//
#include <hip/hip_runtime.h>
#include <math.h>

#define NB 4
#define NN 512

// ---------------- kA: ha = X@Wa + b1, hb = X@Wb ; zero ru ----------------
__global__ void kA(const float* __restrict__ X, const float* __restrict__ W1,
                   const float* __restrict__ b1, float* __restrict__ ha,
                   float* __restrict__ hb, float* __restrict__ ru) {
  int b = blockIdx.y, n0 = blockIdx.x * 8;
  __shared__ float xs[8][128];
  int t = threadIdx.x;  // 128 threads
  for (int q = t; q < 1024; q += 128) {
    int r = q >> 7, f = q & 127;
    xs[r][f] = X[(size_t)(b * NN + n0 + r) * 128 + f];
  }
  int flat = b * 64 + blockIdx.x;
  if (flat < 16) ru[flat * 128 + t] = 0.f;
  __syncthreads();
  float accA[8] = {0,0,0,0,0,0,0,0}, accB[8] = {0,0,0,0,0,0,0,0};
  for (int f = 0; f < 128; ++f) {
    float wa = W1[f * 128 + t];
    float wb = W1[(128 + f) * 128 + t];
#pragma unroll
    for (int r = 0; r < 8; ++r) {
      accA[r] = fmaf(xs[r][f], wa, accA[r]);
      accB[r] = fmaf(xs[r][f], wb, accB[r]);
    }
  }
  float b1v = b1[t];
#pragma unroll
  for (int r = 0; r < 8; ++r) {
    ha[(size_t)(b * NN + n0 + r) * 128 + t] = accA[r] + b1v;
    hb[(size_t)(b * NN + n0 + r) * 128 + t] = accB[r];
  }
}

// ------- kB: K = exp(-5*cost), cost = relu(ha_i+hb_j+dist*wd)@W2 + b2 ----
__global__ void kB(const float* __restrict__ ha, const float* __restrict__ hb,
                   const float* __restrict__ coords, const float* __restrict__ W1,
                   const float* __restrict__ W2, const float* __restrict__ b2,
                   float* __restrict__ Km, float* __restrict__ ru) {
  int b = blockIdx.z, i0 = blockIdx.y * 32, j0 = blockIdx.x * 32;
  __shared__ alignas(16) float As[32][132];
  __shared__ alignas(16) float Bs[32][132];
  __shared__ alignas(16) float wd[128];
  __shared__ alignas(16) float w2[128];
  __shared__ float ci[32][3], cj[32][3];
  int t = threadIdx.x;  // 256
  for (int q = t; q < 1024; q += 256) {
    int r = q >> 5, c = (q & 31) * 4;
    *(float4*)&As[r][c] = *(const float4*)&ha[(size_t)(b * NN + i0 + r) * 128 + c];
    *(float4*)&Bs[r][c] = *(const float4*)&hb[(size_t)(b * NN + j0 + r) * 128 + c];
  }
  if (t < 128) { wd[t] = W1[256 * 128 + t]; w2[t] = W2[t]; }
  if (t < 96) ((float*)ci)[t] = coords[(size_t)(b * NN + i0) * 3 + t];
  else if (t < 192) ((float*)cj)[t - 96] = coords[(size_t)(b * NN + j0) * 3 + (t - 96)];
  __syncthreads();
  int tx = t & 15, ty = t >> 4;
  int ia = 2 * ty, ib = ia + 1, ja = tx, jb = tx + 16;
  float d00, d01, d10, d11;
  {
    float ax = ci[ia][0], ay = ci[ia][1], az = ci[ia][2];
    float bx = ci[ib][0], by = ci[ib][1], bz = ci[ib][2];
    float cx0 = cj[ja][0], cy0 = cj[ja][1], cz0 = cj[ja][2];
    float cx1 = cj[jb][0], cy1 = cj[jb][1], cz1 = cj[jb][2];
    float dx, dy, dz;
    dx = ax - cx0; dy = ay - cy0; dz = az - cz0;
    d00 = sqrtf(fmaxf(dx * dx + dy * dy + dz * dz, 0.f));
    dx = ax - cx1; dy = ay - cy1; dz = az - cz1;
    d01 = sqrtf(fmaxf(dx * dx + dy * dy + dz * dz, 0.f));
    dx = bx - cx0; dy = by - cy0; dz = bz - cz0;
    d10 = sqrtf(fmaxf(dx * dx + dy * dy + dz * dz, 0.f));
    dx = bx - cx1; dy = by - cy1; dz = bz - cz1;
    d11 = sqrtf(fmaxf(dx * dx + dy * dy + dz * dz, 0.f));
  }
  float a00 = 0, a01 = 0, a10 = 0, a11 = 0;
  for (int k = 0; k < 128; k += 4) {
    float4 A0 = *(float4*)&As[ia][k];
    float4 A1 = *(float4*)&As[ib][k];
    float4 B0 = *(float4*)&Bs[ja][k];
    float4 B1 = *(float4*)&Bs[jb][k];
    float4 W = *(float4*)&wd[k];
    float4 V = *(float4*)&w2[k];
#pragma unroll
    for (int kk = 0; kk < 4; ++kk) {
      float av = ((float*)&A0)[kk], av1 = ((float*)&A1)[kk];
      float bv = ((float*)&B0)[kk], bv1 = ((float*)&B1)[kk];
      float wv = ((float*)&W)[kk], vv = ((float*)&V)[kk];
      float t00 = fmaxf(fmaf(d00, wv, av + bv), 0.f);
      float t01 = fmaxf(fmaf(d01, wv, av + bv1), 0.f);
      float t10 = fmaxf(fmaf(d10, wv, av1 + bv), 0.f);
      float t11 = fmaxf(fmaf(d11, wv, av1 + bv1), 0.f);
      a00 = fmaf(t00, vv, a00);
      a01 = fmaf(t01, vv, a01);
      a10 = fmaf(t10, vv, a10);
      a11 = fmaf(t11, vv, a11);
    }
  }
  float b2v = b2[0];
  float k00 = __expf(-5.0f * (a00 + b2v));
  float k01 = __expf(-5.0f * (a01 + b2v));
  float k10 = __expf(-5.0f * (a10 + b2v));
  float k11 = __expf(-5.0f * (a11 + b2v));
  size_t r0 = (size_t)(b * NN + i0 + ia) * NN + j0;
  size_t r1 = (size_t)(b * NN + i0 + ib) * NN + j0;
  Km[r0 + ja] = k00; Km[r0 + jb] = k01;
  Km[r1 + ja] = k10; Km[r1 + jb] = k11;
  float s0 = k00 + k01, s1 = k10 + k11;
#pragma unroll
  for (int off = 1; off < 16; off <<= 1) {
    s0 += __shfl_xor(s0, off);
    s1 += __shfl_xor(s1, off);
  }
  if (tx == 0) {
    atomicAdd(&ru[b * NN + i0 + ia], s0);
    atomicAdd(&ru[b * NN + i0 + ib], s1);
  }
}

// ------- kCcol: rvp[ic] = partial col sums of K * (1/ru) -----------------
__global__ void kCcol(const float* __restrict__ Km, const float* __restrict__ ru,
                      float* __restrict__ rvp) {
  int ic = blockIdx.x, jc = blockIdx.y, b = blockIdx.z;
  __shared__ float uinv[64];
  int t = threadIdx.x;  // 256
  if (t < 64) uinv[t] = 1.0f / ru[b * NN + ic * 64 + t];
  __syncthreads();
  int j = jc * 256 + t;
  const float* Kp = Km + (size_t)(b * NN + ic * 64) * NN + j;
  float acc = 0.f;
#pragma unroll 8
  for (int ii = 0; ii < 64; ++ii) acc = fmaf(Kp[(size_t)ii * NN], uinv[ii], acc);
  rvp[ic * 2048 + b * NN + j] = acc;
}

// ------- kCrc: fused Sinkhorn iteration (row pass + col partials) --------
// Block (ic,b): vinv from rvpOld (all partials), ru/uinv for its 64 rows,
// then new col partials rvpNew[ic] using only its own uinv rows.
__global__ void kCrc(const float* __restrict__ Km, const float* __restrict__ rvpOld,
                     float* __restrict__ rvpNew, float* __restrict__ ru) {
  int ic = blockIdx.x, b = blockIdx.y;
  __shared__ float vinv[512];
  __shared__ float uinv[64];
  int t = threadIdx.x;  // 256
  for (int j = t; j < 512; j += 256) {
    float s = 0.f;
#pragma unroll
    for (int q = 0; q < 8; ++q) s += rvpOld[q * 2048 + b * NN + j];
    vinv[j] = 1.0f / s;
  }
  __syncthreads();
  int w = t >> 6, l = t & 63;
  for (int m = 0; m < 16; ++m) {
    int r = ic * 64 + w * 16 + m;
    const float* Kp = Km + (size_t)(b * NN + r) * NN;
    float acc = 0.f;
#pragma unroll
    for (int mm = 0; mm < 8; ++mm) acc = fmaf(Kp[l + 64 * mm], vinv[l + 64 * mm], acc);
#pragma unroll
    for (int off = 1; off < 64; off <<= 1) acc += __shfl_xor(acc, off);
    if (l == 0) { uinv[w * 16 + m] = 1.0f / acc; ru[b * NN + r] = acc; }
  }
  __syncthreads();
  for (int j = t; j < 512; j += 256) {
    const float* Kp = Km + (size_t)(b * NN + ic * 64) * NN + j;
    float acc = 0.f;
#pragma unroll 8
    for (int ii = 0; ii < 64; ++ii) acc = fmaf(Kp[(size_t)ii * NN], uinv[ii], acc);
    rvpNew[ic * 2048 + b * NN + j] = acc;
  }
}

// ------- kAdj: adj = (1/ru_i) * K * (1/rv_j) -----------------------------
__global__ void kAdj(const float* __restrict__ Km, const float* __restrict__ ru,
                     const float* __restrict__ rvp, float* __restrict__ out) {
  int rc = blockIdx.x, b = blockIdx.y;
  __shared__ float vinv[512];
  __shared__ float uinv[64];
  int t = threadIdx.x;  // 256
  for (int j = t; j < 512; j += 256) {
    float s = 0.f;
#pragma unroll
    for (int ic = 0; ic < 8; ++ic) s += rvp[ic * 2048 + b * NN + j];
    vinv[j] = 1.0f / s;
  }
  if (t < 64) uinv[t] = 1.0f / ru[b * NN + rc * 64 + t];
  __syncthreads();
  for (int m = 0; m < 64; ++m) {
    int r = rc * 64 + m;
    float u = uinv[m];
    const float* Kp = Km + (size_t)(b * NN + r) * NN;
    float* op = out + (size_t)(b * NN + r) * NN;
    for (int j = t; j < 512; j += 256) op[j] = Kp[j] * u * vinv[j];
  }
}

// ------- kG1: xw = x @ Wg[l]  (2048x512, K=128) ---------------------------
__global__ void kG1(const float* __restrict__ x, const float* __restrict__ Wg,
                    float* __restrict__ xw) {
  int b = blockIdx.y, n0 = blockIdx.x * 8;
  __shared__ float xs[8][128];
  int t = threadIdx.x;  // 256
  for (int q = t; q < 1024; q += 256) {
    int r = q >> 7, f = q & 127;
    xs[r][f] = x[(size_t)(b * NN + n0 + r) * 128 + f];
  }
  __syncthreads();
  int c0 = t, c1 = t + 256;
  float acc0[8] = {0,0,0,0,0,0,0,0}, acc1[8] = {0,0,0,0,0,0,0,0};
  for (int f = 0; f < 128; ++f) {
    float w0 = Wg[f * 512 + c0], w1 = Wg[f * 512 + c1];
#pragma unroll
    for (int r = 0; r < 8; ++r) {
      float xv = xs[r][f];
      acc0[r] = fmaf(xv, w0, acc0[r]);
      acc1[r] = fmaf(xv, w1, acc1[r]);
    }
  }
#pragma unroll
  for (int r = 0; r < 8; ++r) {
    xw[(size_t)(b * NN + n0 + r) * 512 + c0] = acc0[r];
    xw[(size_t)(b * NN + n0 + r) * 512 + c1] = acc1[r];
  }
}

// ------- kG1b: s_src/s_dst (transposed layout [b*4+h][n]) ----------------
__global__ void kG1b(const float* __restrict__ xw, const float* __restrict__ asrc,
                     const float* __restrict__ adst, float* __restrict__ ssT,
                     float* __restrict__ sdT) {
  int n = blockIdx.x, b = blockIdx.y;
  int t = threadIdx.x;  // 128
  const float* row = xw + (size_t)(b * NN + n) * 512;
  float ps[4], pd[4];
#pragma unroll
  for (int q = 0; q < 4; ++q) {
    int c = q * 128 + t;
    float v = row[c];
    ps[q] = v * asrc[c];
    pd[q] = v * adst[c];
  }
#pragma unroll
  for (int off = 1; off < 64; off <<= 1) {
#pragma unroll
    for (int q = 0; q < 4; ++q) {
      ps[q] += __shfl_xor(ps[q], off);
      pd[q] += __shfl_xor(pd[q], off);
    }
  }
  __shared__ float part[2][8];
  int w = t >> 6, l = t & 63;
  if (l == 0) {
#pragma unroll
    for (int q = 0; q < 4; ++q) { part[w][q] = ps[q]; part[w][4 + q] = pd[q]; }
  }
  __syncthreads();
  if (t < 8) {
    float s = part[0][t] + part[1][t];
    int h = t & 3;
    if (t < 4) ssT[(size_t)(b * 4 + h) * 512 + n] = s;
    else       sdT[(size_t)(b * 4 + h) * 512 + n] = s;
  }
}

// ------- kSmax: ssmax[b*4+h] = max_n ssT[b*4+h][n] -----------------------
__global__ void kSmax(const float* __restrict__ ssT, float* __restrict__ ssmax) {
  int h = blockIdx.x, b = blockIdx.y;
  int t = threadIdx.x;  // 512
  float v = ssT[(size_t)(b * 4 + h) * 512 + t];
#pragma unroll
  for (int off = 1; off < 64; off <<= 1) v = fmaxf(v, __shfl_xor(v, off));
  __shared__ float wp[8];
  int w = t >> 6, l = t & 63;
  if (l == 0) wp[w] = v;
  __syncthreads();
  if (t == 0) {
    float m = wp[0];
#pragma unroll
    for (int q = 1; q < 8; ++q) m = fmaxf(m, wp[q]);
    ssmax[b * 4 + h] = m;
  }
}

// ------- kG2s: per (b,h,16-row tile): P in LDS + in-block j-split PV -----
// partial[(b*4+h)*512 + i][f] = sum_j softmax_p(i,j) * xw[b,j,h,f] / 4
#define PLD 520
__global__ __launch_bounds__(512) void kG2s(const float* __restrict__ xw,
                                            const float* __restrict__ ssT,
                                            const float* __restrict__ sdT,
                                            const float* __restrict__ ssmax,
                                            float* __restrict__ partial) {
  int b = blockIdx.z, h = blockIdx.y, i0 = blockIdx.x * 16;
  int bh = b * 4 + h;
  __shared__ float ss[512];
  __shared__ alignas(16) float pl[16][PLD];
  __shared__ float sdl[16], mxl[16], idl[16];
  int t = threadIdx.x;  // 512
  if (t < 512) ss[t] = ssT[(size_t)bh * 512 + t];
  if (t < 16) {
    float sdv = sdT[(size_t)bh * 512 + i0 + t];
    sdl[t] = sdv;
    float m = sdv + ssmax[bh];
    mxl[t] = (m >= 0.f) ? m : 0.2f * m;
  }
  __syncthreads();
  // phase A: thread (il = t>>5, jq = t&31) -> j = jj*32 + jq (conflict-free)
  {
    int il = t >> 5, jq = t & 31;
    float mx = mxl[il], sdv = sdl[il];
    float den = 0.f;
#pragma unroll
    for (int jj = 0; jj < 16; ++jj) {
      int j = jj * 32 + jq;
      float e = sdv + ss[j];
      e = (e >= 0.f) ? e : 0.2f * e;
      float pe = __expf(e - mx);
      pl[il][j] = pe;
      den += pe;
    }
#pragma unroll
    for (int off = 1; off < 32; off <<= 1) den += __shfl_xor(den, off);
    if (jq == 0) idl[il] = 1.0f / (4.0f * den);
  }
  __syncthreads();
  // phase B: thread (jh = t>>8, r8 = (t>>5)&7, fq = t&31)
  // rows r8, r8+8; j in [jh*256, jh*256+256), 2 j per iter
  int jh = t >> 8, r8 = (t >> 5) & 7, fq = t & 31;
  const float* xp = xw + (size_t)(b * NN) * 512 + h * 128 + fq * 4;
  float4 a0 = {0,0,0,0}, a1 = {0,0,0,0};
  int jbase = jh * 256;
#pragma unroll 4
  for (int jj = 0; jj < 256; jj += 2) {
    int j = jbase + jj;
    float4 xv0 = *(const float4*)&xp[(size_t)j * 512];
    float4 xv1 = *(const float4*)&xp[(size_t)(j + 1) * 512];
    float2 p0 = *(const float2*)&pl[r8][j];
    float2 p1 = *(const float2*)&pl[r8 + 8][j];
    a0.x = fmaf(p0.x, xv0.x, a0.x); a0.y = fmaf(p0.x, xv0.y, a0.y);
    a0.z = fmaf(p0.x, xv0.z, a0.z); a0.w = fmaf(p0.x, xv0.w, a0.w);
    a1.x = fmaf(p1.x, xv0.x, a1.x); a1.y = fmaf(p1.x, xv0.y, a1.y);
    a1.z = fmaf(p1.x, xv0.z, a1.z); a1.w = fmaf(p1.x, xv0.w, a1.w);
    a0.x = fmaf(p0.y, xv1.x, a0.x); a0.y = fmaf(p0.y, xv1.y, a0.y);
    a0.z = fmaf(p0.y, xv1.z, a0.z); a0.w = fmaf(p0.y, xv1.w, a0.w);
    a1.x = fmaf(p1.y, xv1.x, a1.x); a1.y = fmaf(p1.y, xv1.y, a1.y);
    a1.z = fmaf(p1.y, xv1.z, a1.z); a1.w = fmaf(p1.y, xv1.w, a1.w);
  }
  __syncthreads();
  // reuse pl as reduce scratch: idx = (row*32 + fq)*2 + jh  (float4 units)
  float4* sc4 = (float4*)pl;
  sc4[((r8 * 32 + fq) * 2) + jh] = a0;
  sc4[(((r8 + 8) * 32 + fq) * 2) + jh] = a1;
  __syncthreads();
  if (t < 256) {
    int rr = (t >> 5) & 7, ff = t & 31;
    float4 u0a = sc4[(rr * 32 + ff) * 2 + 0];
    float4 u0b = sc4[(rr * 32 + ff) * 2 + 1];
    float4 u1a = sc4[((rr + 8) * 32 + ff) * 2 + 0];
    float4 u1b = sc4[((rr + 8) * 32 + ff) * 2 + 1];
    float s0 = idl[rr], s1 = idl[rr + 8];
    float4 o0, o1;
    o0.x = (u0a.x + u0b.x) * s0; o0.y = (u0a.y + u0b.y) * s0;
    o0.z = (u0a.z + u0b.z) * s0; o0.w = (u0a.w + u0b.w) * s0;
    o1.x = (u1a.x + u1b.x) * s1; o1.y = (u1a.y + u1b.y) * s1;
    o1.z = (u1a.z + u1b.z) * s1; o1.w = (u1a.w + u1b.w) * s1;
    *(float4*)&partial[((size_t)bh * NN + i0 + rr) * 128 + ff * 4] = o0;
    *(float4*)&partial[((size_t)bh * NN + i0 + rr + 8) * 128 + ff * 4] = o1;
  }
}

// ------- kRed: xo[b,i,f] = sum_h partial[b,h,i,f] + bg[f] ----------------
__global__ void kRed(const float* __restrict__ partial, const float* __restrict__ bg,
                     float* __restrict__ xo) {
  int idx = blockIdx.x * 256 + threadIdx.x;  // float4 index, 65536 total
  int f4 = idx & 31;
  int rest = idx >> 5;           // b*512 + i
  int b = rest >> 9, i = rest & 511;
  const float* pp = partial + (((size_t)b * 4) * NN + i) * 128 + f4 * 4;
  float4 s = *(const float4*)pp;
  const float* p1 = pp + (size_t)NN * 128;
  const float* p2 = pp + (size_t)2 * NN * 128;
  const float* p3 = pp + (size_t)3 * NN * 128;
  float4 v1 = *(const float4*)p1, v2 = *(const float4*)p2, v3 = *(const float4*)p3;
  float4 bb = *(const float4*)&bg[f4 * 4];
  s.x += v1.x + v2.x + v3.x + bb.x;
  s.y += v1.y + v2.y + v3.y + bb.y;
  s.z += v1.z + v2.z + v3.z + bb.z;
  s.w += v1.w + v2.w + v3.w + bb.w;
  *(float4*)&xo[(size_t)rest * 128 + f4 * 4] = s;
}

// ------- kF: final_adj = sigmoid(x @ x^T) --------------------------------
__global__ void kF(const float* __restrict__ x, float* __restrict__ out) {
  int b = blockIdx.z, i0 = blockIdx.y * 32, j0 = blockIdx.x * 32;
  __shared__ alignas(16) float As[32][132];
  __shared__ alignas(16) float Bs[32][132];
  int t = threadIdx.x;  // 256
  for (int q = t; q < 1024; q += 256) {
    int r = q >> 5, c = (q & 31) * 4;
    *(float4*)&As[r][c] = *(const float4*)&x[(size_t)(b * NN + i0 + r) * 128 + c];
    *(float4*)&Bs[r][c] = *(const float4*)&x[(size_t)(b * NN + j0 + r) * 128 + c];
  }
  __syncthreads();
  int tx = t & 15, ty = t >> 4;
  int ia = 2 * ty, ib = ia + 1, ja = tx, jb = tx + 16;
  float a00 = 0, a01 = 0, a10 = 0, a11 = 0;
  for (int k = 0; k < 128; k += 4) {
    float4 A0 = *(float4*)&As[ia][k];
    float4 A1 = *(float4*)&As[ib][k];
    float4 B0 = *(float4*)&Bs[ja][k];
    float4 B1 = *(float4*)&Bs[jb][k];
#pragma unroll
    for (int kk = 0; kk < 4; ++kk) {
      float av = ((float*)&A0)[kk], av1 = ((float*)&A1)[kk];
      float bv = ((float*)&B0)[kk], bv1 = ((float*)&B1)[kk];
      a00 = fmaf(av, bv, a00);
      a01 = fmaf(av, bv1, a01);
      a10 = fmaf(av1, bv, a10);
      a11 = fmaf(av1, bv1, a11);
    }
  }
  size_t r0 = (size_t)(b * NN + i0 + ia) * NN + j0;
  size_t r1 = (size_t)(b * NN + i0 + ib) * NN + j0;
  out[r0 + ja] = 1.0f / (1.0f + __expf(-a00));
  out[r0 + jb] = 1.0f / (1.0f + __expf(-a01));
  out[r1 + ja] = 1.0f / (1.0f + __expf(-a10));
  out[r1 + jb] = 1.0f / (1.0f + __expf(-a11));
}

extern "C" void kernel_launch(void* const* d_in, const int* in_sizes, int n_in,
                              void* d_out, int out_size, void* d_ws, size_t ws_size,
                              hipStream_t stream) {
  (void)in_sizes; (void)n_in; (void)out_size; (void)ws_size;
  const float* X   = (const float*)d_in[0];
  const float* C   = (const float*)d_in[1];
  const float* W1  = (const float*)d_in[2];
  const float* b1  = (const float*)d_in[3];
  const float* W2  = (const float*)d_in[4];
  const float* b2  = (const float*)d_in[5];
  const float* Wg  = (const float*)d_in[6];
  const float* as_ = (const float*)d_in[7];
  const float* ad_ = (const float*)d_in[8];
  const float* bg  = (const float*)d_in[9];
  float* out = (float*)d_out;
  float* ws = (float*)d_ws;

  float* ha    = ws;                 // 262144
  float* hb    = ws + 262144;        // 262144
  float* Km    = ws + 524288;        // 1048576
  float* ru    = ws + 1572864;       // 2048
  float* rvpA  = ws + 1574912;       // 16384 (8 x 2048)
  float* xw    = ws + 1591296;       // 1048576
  float* ssT   = ws + 2639872;       // 8192
  float* sdT   = ws + 2648064;       // 8192
  float* x1    = ws + 2656256;       // 262144
  float* x2    = ws + 2918400;       // 262144
  float* ssmax = ws + 3180544;       // 16
  float* rvpB  = ws + 3180560;       // 16384
  float* partial = Km;               // alias: Km is dead after kAdj

  kA<<<dim3(64, 4), 128, 0, stream>>>(X, W1, b1, ha, hb, ru);
  kB<<<dim3(16, 16, 4), 256, 0, stream>>>(ha, hb, C, W1, W2, b2, Km, ru);
  // Sinkhorn: kB produced ru (row sums); kCcol -> rvpA; then 9 fused iters
  kCcol<<<dim3(8, 2, 4), 256, 0, stream>>>(Km, ru, rvpA);
  for (int it = 0; it < 9; ++it) {
    const float* src = (it & 1) ? rvpB : rvpA;
    float* dst = (it & 1) ? rvpA : rvpB;
    kCrc<<<dim3(8, 4), 256, 0, stream>>>(Km, src, dst, ru);
  }
  kAdj<<<dim3(8, 4), 256, 0, stream>>>(Km, ru, rvpB, out + 1048576);
  // GAT layer 0
  kG1<<<dim3(64, 4), 256, 0, stream>>>(X, Wg, xw);
  kG1b<<<dim3(512, 4), 128, 0, stream>>>(xw, as_, ad_, ssT, sdT);
  kSmax<<<dim3(4, 4), 512, 0, stream>>>(ssT, ssmax);
  kG2s<<<dim3(32, 4, 4), 512, 0, stream>>>(xw, ssT, sdT, ssmax, partial);
  kRed<<<256, 256, 0, stream>>>(partial, bg, x1);
  // GAT layer 1
  kG1<<<dim3(64, 4), 256, 0, stream>>>(x1, Wg + 65536, xw);
  kG1b<<<dim3(512, 4), 128, 0, stream>>>(xw, as_ + 512, ad_ + 512, ssT, sdT);
  kSmax<<<dim3(4, 4), 512, 0, stream>>>(ssT, ssmax);
  kG2s<<<dim3(32, 4, 4), 512, 0, stream>>>(xw, ssT, sdT, ssmax, partial);
  kRed<<<256, 256, 0, stream>>>(partial, bg + 128, x2);
  // final adjacency
  kF<<<dim3(16, 16, 4), 256, 0, stream>>>(x2, out);
}

// Round 4
// 241.144 us; speedup vs baseline: 1.4863x; 1.2779x over previous
//
#include <hip/hip_runtime.h>
#include <math.h>

#define NB 4
#define NN 512

// ---------------- kA: ha = X@Wa + b1, hb = X@Wb ; zero ru ----------------
__global__ void kA(const float* __restrict__ X, const float* __restrict__ W1,
                   const float* __restrict__ b1, float* __restrict__ ha,
                   float* __restrict__ hb, float* __restrict__ ru) {
  int b = blockIdx.y, n0 = blockIdx.x * 8;
  __shared__ float xs[8][128];
  int t = threadIdx.x;  // 128 threads
  for (int q = t; q < 1024; q += 128) {
    int r = q >> 7, f = q & 127;
    xs[r][f] = X[(size_t)(b * NN + n0 + r) * 128 + f];
  }
  int flat = b * 64 + blockIdx.x;
  if (flat < 16) ru[flat * 128 + t] = 0.f;
  __syncthreads();
  float accA[8] = {0,0,0,0,0,0,0,0}, accB[8] = {0,0,0,0,0,0,0,0};
  for (int f = 0; f < 128; ++f) {
    float wa = W1[f * 128 + t];
    float wb = W1[(128 + f) * 128 + t];
#pragma unroll
    for (int r = 0; r < 8; ++r) {
      accA[r] = fmaf(xs[r][f], wa, accA[r]);
      accB[r] = fmaf(xs[r][f], wb, accB[r]);
    }
  }
  float b1v = b1[t];
#pragma unroll
  for (int r = 0; r < 8; ++r) {
    ha[(size_t)(b * NN + n0 + r) * 128 + t] = accA[r] + b1v;
    hb[(size_t)(b * NN + n0 + r) * 128 + t] = accB[r];
  }
}

// ------- kB: K = exp(-5*cost), cost = relu(ha_i+hb_j+dist*wd)@W2 + b2 ----
__global__ void kB(const float* __restrict__ ha, const float* __restrict__ hb,
                   const float* __restrict__ coords, const float* __restrict__ W1,
                   const float* __restrict__ W2, const float* __restrict__ b2,
                   float* __restrict__ Km, float* __restrict__ ru) {
  int b = blockIdx.z, i0 = blockIdx.y * 32, j0 = blockIdx.x * 32;
  __shared__ alignas(16) float As[32][132];
  __shared__ alignas(16) float Bs[32][132];
  __shared__ alignas(16) float wd[128];
  __shared__ alignas(16) float w2[128];
  __shared__ float ci[32][3], cj[32][3];
  int t = threadIdx.x;  // 256
  for (int q = t; q < 1024; q += 256) {
    int r = q >> 5, c = (q & 31) * 4;
    *(float4*)&As[r][c] = *(const float4*)&ha[(size_t)(b * NN + i0 + r) * 128 + c];
    *(float4*)&Bs[r][c] = *(const float4*)&hb[(size_t)(b * NN + j0 + r) * 128 + c];
  }
  if (t < 128) { wd[t] = W1[256 * 128 + t]; w2[t] = W2[t]; }
  if (t < 96) ((float*)ci)[t] = coords[(size_t)(b * NN + i0) * 3 + t];
  else if (t < 192) ((float*)cj)[t - 96] = coords[(size_t)(b * NN + j0) * 3 + (t - 96)];
  __syncthreads();
  int tx = t & 15, ty = t >> 4;
  int ia = 2 * ty, ib = ia + 1, ja = tx, jb = tx + 16;
  float d00, d01, d10, d11;
  {
    float ax = ci[ia][0], ay = ci[ia][1], az = ci[ia][2];
    float bx = ci[ib][0], by = ci[ib][1], bz = ci[ib][2];
    float cx0 = cj[ja][0], cy0 = cj[ja][1], cz0 = cj[ja][2];
    float cx1 = cj[jb][0], cy1 = cj[jb][1], cz1 = cj[jb][2];
    float dx, dy, dz;
    dx = ax - cx0; dy = ay - cy0; dz = az - cz0;
    d00 = sqrtf(fmaxf(dx * dx + dy * dy + dz * dz, 0.f));
    dx = ax - cx1; dy = ay - cy1; dz = az - cz1;
    d01 = sqrtf(fmaxf(dx * dx + dy * dy + dz * dz, 0.f));
    dx = bx - cx0; dy = by - cy0; dz = bz - cz0;
    d10 = sqrtf(fmaxf(dx * dx + dy * dy + dz * dz, 0.f));
    dx = bx - cx1; dy = by - cy1; dz = bz - cz1;
    d11 = sqrtf(fmaxf(dx * dx + dy * dy + dz * dz, 0.f));
  }
  float a00 = 0, a01 = 0, a10 = 0, a11 = 0;
  for (int k = 0; k < 128; k += 4) {
    float4 A0 = *(float4*)&As[ia][k];
    float4 A1 = *(float4*)&As[ib][k];
    float4 B0 = *(float4*)&Bs[ja][k];
    float4 B1 = *(float4*)&Bs[jb][k];
    float4 W = *(float4*)&wd[k];
    float4 V = *(float4*)&w2[k];
#pragma unroll
    for (int kk = 0; kk < 4; ++kk) {
      float av = ((float*)&A0)[kk], av1 = ((float*)&A1)[kk];
      float bv = ((float*)&B0)[kk], bv1 = ((float*)&B1)[kk];
      float wv = ((float*)&W)[kk], vv = ((float*)&V)[kk];
      float t00 = fmaxf(fmaf(d00, wv, av + bv), 0.f);
      float t01 = fmaxf(fmaf(d01, wv, av + bv1), 0.f);
      float t10 = fmaxf(fmaf(d10, wv, av1 + bv), 0.f);
      float t11 = fmaxf(fmaf(d11, wv, av1 + bv1), 0.f);
      a00 = fmaf(t00, vv, a00);
      a01 = fmaf(t01, vv, a01);
      a10 = fmaf(t10, vv, a10);
      a11 = fmaf(t11, vv, a11);
    }
  }
  float b2v = b2[0];
  float k00 = __expf(-5.0f * (a00 + b2v));
  float k01 = __expf(-5.0f * (a01 + b2v));
  float k10 = __expf(-5.0f * (a10 + b2v));
  float k11 = __expf(-5.0f * (a11 + b2v));
  size_t r0 = (size_t)(b * NN + i0 + ia) * NN + j0;
  size_t r1 = (size_t)(b * NN + i0 + ib) * NN + j0;
  Km[r0 + ja] = k00; Km[r0 + jb] = k01;
  Km[r1 + ja] = k10; Km[r1 + jb] = k11;
  float s0 = k00 + k01, s1 = k10 + k11;
#pragma unroll
  for (int off = 1; off < 16; off <<= 1) {
    s0 += __shfl_xor(s0, off);
    s1 += __shfl_xor(s1, off);
  }
  if (tx == 0) {
    atomicAdd(&ru[b * NN + i0 + ia], s0);
    atomicAdd(&ru[b * NN + i0 + ib], s1);
  }
}

// ------- kCcol: rvp[ic] = partial col sums of K * (1/ru), 512 thr --------
__global__ void kCcol(const float* __restrict__ Km, const float* __restrict__ ru,
                      float* __restrict__ rvp) {
  int ic = blockIdx.x, b = blockIdx.y;
  __shared__ float uinv[64];
  int t = threadIdx.x;  // 512
  if (t < 64) uinv[t] = 1.0f / ru[b * NN + ic * 64 + t];
  __syncthreads();
  const float* Kp = Km + (size_t)(b * NN + ic * 64) * NN + t;
  float acc = 0.f;
#pragma unroll 8
  for (int ii = 0; ii < 64; ++ii) acc = fmaf(Kp[(size_t)ii * NN], uinv[ii], acc);
  rvp[ic * 2048 + b * NN + t] = acc;
}

// ------- kCrc: fused Sinkhorn iteration (row pass + col partials), 512 thr
__global__ __launch_bounds__(512) void kCrc(const float* __restrict__ Km,
                                            const float* __restrict__ rvpOld,
                                            float* __restrict__ rvpNew,
                                            float* __restrict__ ru) {
  int ic = blockIdx.x, b = blockIdx.y;
  __shared__ float vinv[512];
  __shared__ float uinv[64];
  int t = threadIdx.x;  // 512
  {
    float s = 0.f;
#pragma unroll
    for (int q = 0; q < 8; ++q) s += rvpOld[q * 2048 + b * NN + t];
    vinv[t] = 1.0f / s;
  }
  __syncthreads();
  int w = t >> 6, l = t & 63;  // 8 waves, 8 rows each
  for (int m = 0; m < 8; ++m) {
    int r = ic * 64 + w * 8 + m;
    const float* Kp = Km + (size_t)(b * NN + r) * NN;
    float acc = 0.f;
#pragma unroll
    for (int mm = 0; mm < 8; ++mm) acc = fmaf(Kp[l + 64 * mm], vinv[l + 64 * mm], acc);
#pragma unroll
    for (int off = 1; off < 64; off <<= 1) acc += __shfl_xor(acc, off);
    if (l == 0) { uinv[w * 8 + m] = 1.0f / acc; ru[b * NN + r] = acc; }
  }
  __syncthreads();
  {
    const float* Kp = Km + (size_t)(b * NN + ic * 64) * NN + t;
    float acc = 0.f;
#pragma unroll 8
    for (int ii = 0; ii < 64; ++ii) acc = fmaf(Kp[(size_t)ii * NN], uinv[ii], acc);
    rvpNew[ic * 2048 + b * NN + t] = acc;
  }
}

// ------- kAdj: adj = (1/ru_i) * K * (1/rv_j), 512 thr --------------------
__global__ __launch_bounds__(512) void kAdj(const float* __restrict__ Km,
                                            const float* __restrict__ ru,
                                            const float* __restrict__ rvp,
                                            float* __restrict__ out) {
  int rc = blockIdx.x, b = blockIdx.y;
  __shared__ float vinv[512];
  __shared__ float uinv[64];
  int t = threadIdx.x;  // 512
  {
    float s = 0.f;
#pragma unroll
    for (int ic = 0; ic < 8; ++ic) s += rvp[ic * 2048 + b * NN + t];
    vinv[t] = 1.0f / s;
  }
  if (t < 64) uinv[t] = 1.0f / ru[b * NN + rc * 64 + t];
  __syncthreads();
  float vj = vinv[t];
  const float* Kp = Km + (size_t)(b * NN + rc * 64) * NN + t;
  float* op = out + (size_t)(b * NN + rc * 64) * NN + t;
#pragma unroll 4
  for (int m = 0; m < 64; ++m) {
    op[(size_t)m * NN] = Kp[(size_t)m * NN] * uinv[m] * vj;
  }
}

// ------- kG1: xw = x @ Wg[l]  (2048x512, K=128) ---------------------------
__global__ void kG1(const float* __restrict__ x, const float* __restrict__ Wg,
                    float* __restrict__ xw) {
  int b = blockIdx.y, n0 = blockIdx.x * 8;
  __shared__ float xs[8][128];
  int t = threadIdx.x;  // 256
  for (int q = t; q < 1024; q += 256) {
    int r = q >> 7, f = q & 127;
    xs[r][f] = x[(size_t)(b * NN + n0 + r) * 128 + f];
  }
  __syncthreads();
  int c0 = t, c1 = t + 256;
  float acc0[8] = {0,0,0,0,0,0,0,0}, acc1[8] = {0,0,0,0,0,0,0,0};
  for (int f = 0; f < 128; ++f) {
    float w0 = Wg[f * 512 + c0], w1 = Wg[f * 512 + c1];
#pragma unroll
    for (int r = 0; r < 8; ++r) {
      float xv = xs[r][f];
      acc0[r] = fmaf(xv, w0, acc0[r]);
      acc1[r] = fmaf(xv, w1, acc1[r]);
    }
  }
#pragma unroll
  for (int r = 0; r < 8; ++r) {
    xw[(size_t)(b * NN + n0 + r) * 512 + c0] = acc0[r];
    xw[(size_t)(b * NN + n0 + r) * 512 + c1] = acc1[r];
  }
}

// ------- kG1b: s_src/s_dst (transposed layout [b*4+h][n]) ----------------
__global__ void kG1b(const float* __restrict__ xw, const float* __restrict__ asrc,
                     const float* __restrict__ adst, float* __restrict__ ssT,
                     float* __restrict__ sdT) {
  int n = blockIdx.x, b = blockIdx.y;
  int t = threadIdx.x;  // 128
  const float* row = xw + (size_t)(b * NN + n) * 512;
  float ps[4], pd[4];
#pragma unroll
  for (int q = 0; q < 4; ++q) {
    int c = q * 128 + t;
    float v = row[c];
    ps[q] = v * asrc[c];
    pd[q] = v * adst[c];
  }
#pragma unroll
  for (int off = 1; off < 64; off <<= 1) {
#pragma unroll
    for (int q = 0; q < 4; ++q) {
      ps[q] += __shfl_xor(ps[q], off);
      pd[q] += __shfl_xor(pd[q], off);
    }
  }
  __shared__ float part[2][8];
  int w = t >> 6, l = t & 63;
  if (l == 0) {
#pragma unroll
    for (int q = 0; q < 4; ++q) { part[w][q] = ps[q]; part[w][4 + q] = pd[q]; }
  }
  __syncthreads();
  if (t < 8) {
    float s = part[0][t] + part[1][t];
    int h = t & 3;
    if (t < 4) ssT[(size_t)(b * 4 + h) * 512 + n] = s;
    else       sdT[(size_t)(b * 4 + h) * 512 + n] = s;
  }
}

// ------- kG2t: per (b,h,8-row tile): P in LDS + 4-way j-split PV ---------
// partial[(b*4+h)*512 + i][f] = sum_j softmax_p(i,j) * xw[b,j,h,f] / 4
#define PLD8 520
__global__ __launch_bounds__(512) void kG2t(const float* __restrict__ xw,
                                            const float* __restrict__ ssT,
                                            const float* __restrict__ sdT,
                                            float* __restrict__ partial) {
  int b = blockIdx.z, h = blockIdx.y, i0 = blockIdx.x * 8;
  int bh = b * 4 + h;
  __shared__ float ss[512];
  __shared__ alignas(16) float pl[8][PLD8];   // 16640 B; reused as reduce scratch
  __shared__ float sdl[8], mxl[8], idl[8], smaxsh[8];
  int t = threadIdx.x;  // 512
  // load ss + in-block max (replaces kSmax)
  {
    float v = ssT[(size_t)bh * 512 + t];
    ss[t] = v;
#pragma unroll
    for (int off = 1; off < 64; off <<= 1) v = fmaxf(v, __shfl_xor(v, off));
    if ((t & 63) == 0) smaxsh[t >> 6] = v;
  }
  __syncthreads();
  if (t < 8) {
    float m = smaxsh[0];
#pragma unroll
    for (int q = 1; q < 8; ++q) m = fmaxf(m, smaxsh[q]);
    float sdv = sdT[(size_t)bh * 512 + i0 + t];
    sdl[t] = sdv;
    float mm = sdv + m;
    mxl[t] = (mm >= 0.f) ? mm : 0.2f * mm;
  }
  __syncthreads();
  // phase A: il = t>>6 (8 rows), jq = t&63 ; j = jj*64 + jq (conflict-free)
  {
    int il = t >> 6, jq = t & 63;
    float mx = mxl[il], sdv = sdl[il];
    float den = 0.f;
#pragma unroll
    for (int jj = 0; jj < 8; ++jj) {
      int j = jj * 64 + jq;
      float e = sdv + ss[j];
      e = (e >= 0.f) ? e : 0.2f * e;
      float pe = __expf(e - mx);
      pl[il][j] = pe;
      den += pe;
    }
#pragma unroll
    for (int off = 1; off < 64; off <<= 1) den += __shfl_xor(den, off);
    if (jq == 0) idl[il] = 1.0f / (4.0f * den);
  }
  __syncthreads();
  // phase B: fq = t&31, rr = (t>>5)&3 (rows rr, rr+4), jh = t>>7 (4 j-quarters)
  int fq = t & 31, rr = (t >> 5) & 3, jh = t >> 7;
  const float* xp = xw + (size_t)(b * NN) * 512 + h * 128 + fq * 4;
  float4 a0 = {0,0,0,0}, a1 = {0,0,0,0};
  int jbase = jh * 128;
#pragma unroll 4
  for (int jj = 0; jj < 128; jj += 2) {
    int j = jbase + jj;
    float4 xv0 = *(const float4*)&xp[(size_t)j * 512];
    float4 xv1 = *(const float4*)&xp[(size_t)(j + 1) * 512];
    float2 p0 = *(const float2*)&pl[rr][j];
    float2 p1 = *(const float2*)&pl[rr + 4][j];
    a0.x = fmaf(p0.x, xv0.x, a0.x); a0.y = fmaf(p0.x, xv0.y, a0.y);
    a0.z = fmaf(p0.x, xv0.z, a0.z); a0.w = fmaf(p0.x, xv0.w, a0.w);
    a1.x = fmaf(p1.x, xv0.x, a1.x); a1.y = fmaf(p1.x, xv0.y, a1.y);
    a1.z = fmaf(p1.x, xv0.z, a1.z); a1.w = fmaf(p1.x, xv0.w, a1.w);
    a0.x = fmaf(p0.y, xv1.x, a0.x); a0.y = fmaf(p0.y, xv1.y, a0.y);
    a0.z = fmaf(p0.y, xv1.z, a0.z); a0.w = fmaf(p0.y, xv1.w, a0.w);
    a1.x = fmaf(p1.y, xv1.x, a1.x); a1.y = fmaf(p1.y, xv1.y, a1.y);
    a1.z = fmaf(p1.y, xv1.z, a1.z); a1.w = fmaf(p1.y, xv1.w, a1.w);
  }
  __syncthreads();
  // reduce scratch: idx = (row*32 + fq) + 256*jh  (float4 units, conflict-free)
  float4* sc4 = (float4*)pl;
  sc4[(rr * 32 + fq) + 256 * jh] = a0;
  sc4[((rr + 4) * 32 + fq) + 256 * jh] = a1;
  __syncthreads();
  if (t < 256) {
    int r = t >> 5, ff = t & 31;
    float4 u0 = sc4[(r * 32 + ff)];
    float4 u1 = sc4[(r * 32 + ff) + 256];
    float4 u2 = sc4[(r * 32 + ff) + 512];
    float4 u3 = sc4[(r * 32 + ff) + 768];
    float s0 = idl[r];
    float4 o;
    o.x = (u0.x + u1.x + u2.x + u3.x) * s0;
    o.y = (u0.y + u1.y + u2.y + u3.y) * s0;
    o.z = (u0.z + u1.z + u2.z + u3.z) * s0;
    o.w = (u0.w + u1.w + u2.w + u3.w) * s0;
    *(float4*)&partial[((size_t)bh * NN + i0 + r) * 128 + ff * 4] = o;
  }
}

// ------- kRed: xo[b,i,f] = sum_h partial[b,h,i,f] + bg[f] ----------------
__global__ void kRed(const float* __restrict__ partial, const float* __restrict__ bg,
                     float* __restrict__ xo) {
  int idx = blockIdx.x * 256 + threadIdx.x;  // float4 index, 65536 total
  int f4 = idx & 31;
  int rest = idx >> 5;           // b*512 + i
  int b = rest >> 9, i = rest & 511;
  const float* pp = partial + (((size_t)b * 4) * NN + i) * 128 + f4 * 4;
  float4 s = *(const float4*)pp;
  const float* p1 = pp + (size_t)NN * 128;
  const float* p2 = pp + (size_t)2 * NN * 128;
  const float* p3 = pp + (size_t)3 * NN * 128;
  float4 v1 = *(const float4*)p1, v2 = *(const float4*)p2, v3 = *(const float4*)p3;
  float4 bb = *(const float4*)&bg[f4 * 4];
  s.x += v1.x + v2.x + v3.x + bb.x;
  s.y += v1.y + v2.y + v3.y + bb.y;
  s.z += v1.z + v2.z + v3.z + bb.z;
  s.w += v1.w + v2.w + v3.w + bb.w;
  *(float4*)&xo[(size_t)rest * 128 + f4 * 4] = s;
}

// ------- kF: final_adj = sigmoid(x @ x^T) --------------------------------
__global__ void kF(const float* __restrict__ x, float* __restrict__ out) {
  int b = blockIdx.z, i0 = blockIdx.y * 32, j0 = blockIdx.x * 32;
  __shared__ alignas(16) float As[32][132];
  __shared__ alignas(16) float Bs[32][132];
  int t = threadIdx.x;  // 256
  for (int q = t; q < 1024; q += 256) {
    int r = q >> 5, c = (q & 31) * 4;
    *(float4*)&As[r][c] = *(const float4*)&x[(size_t)(b * NN + i0 + r) * 128 + c];
    *(float4*)&Bs[r][c] = *(const float4*)&x[(size_t)(b * NN + j0 + r) * 128 + c];
  }
  __syncthreads();
  int tx = t & 15, ty = t >> 4;
  int ia = 2 * ty, ib = ia + 1, ja = tx, jb = tx + 16;
  float a00 = 0, a01 = 0, a10 = 0, a11 = 0;
  for (int k = 0; k < 128; k += 4) {
    float4 A0 = *(float4*)&As[ia][k];
    float4 A1 = *(float4*)&As[ib][k];
    float4 B0 = *(float4*)&Bs[ja][k];
    float4 B1 = *(float4*)&Bs[jb][k];
#pragma unroll
    for (int kk = 0; kk < 4; ++kk) {
      float av = ((float*)&A0)[kk], av1 = ((float*)&A1)[kk];
      float bv = ((float*)&B0)[kk], bv1 = ((float*)&B1)[kk];
      a00 = fmaf(av, bv, a00);
      a01 = fmaf(av, bv1, a01);
      a10 = fmaf(av1, bv, a10);
      a11 = fmaf(av1, bv1, a11);
    }
  }
  size_t r0 = (size_t)(b * NN + i0 + ia) * NN + j0;
  size_t r1 = (size_t)(b * NN + i0 + ib) * NN + j0;
  out[r0 + ja] = 1.0f / (1.0f + __expf(-a00));
  out[r0 + jb] = 1.0f / (1.0f + __expf(-a01));
  out[r1 + ja] = 1.0f / (1.0f + __expf(-a10));
  out[r1 + jb] = 1.0f / (1.0f + __expf(-a11));
}

extern "C" void kernel_launch(void* const* d_in, const int* in_sizes, int n_in,
                              void* d_out, int out_size, void* d_ws, size_t ws_size,
                              hipStream_t stream) {
  (void)in_sizes; (void)n_in; (void)out_size; (void)ws_size;
  const float* X   = (const float*)d_in[0];
  const float* C   = (const float*)d_in[1];
  const float* W1  = (const float*)d_in[2];
  const float* b1  = (const float*)d_in[3];
  const float* W2  = (const float*)d_in[4];
  const float* b2  = (const float*)d_in[5];
  const float* Wg  = (const float*)d_in[6];
  const float* as_ = (const float*)d_in[7];
  const float* ad_ = (const float*)d_in[8];
  const float* bg  = (const float*)d_in[9];
  float* out = (float*)d_out;
  float* ws = (float*)d_ws;

  float* ha    = ws;                 // 262144
  float* hb    = ws + 262144;        // 262144
  float* Km    = ws + 524288;        // 1048576
  float* ru    = ws + 1572864;       // 2048
  float* rvpA  = ws + 1574912;       // 16384 (8 x 2048)
  float* xw    = ws + 1591296;       // 1048576
  float* ssT   = ws + 2639872;       // 8192
  float* sdT   = ws + 2648064;       // 8192
  float* x1    = ws + 2656256;       // 262144
  float* x2    = ws + 2918400;       // 262144
  float* rvpB  = ws + 3180560;       // 16384
  float* partial = Km;               // alias: Km is dead after kAdj

  kA<<<dim3(64, 4), 128, 0, stream>>>(X, W1, b1, ha, hb, ru);
  kB<<<dim3(16, 16, 4), 256, 0, stream>>>(ha, hb, C, W1, W2, b2, Km, ru);
  // Sinkhorn: kB produced ru (row sums); kCcol -> rvpA; then 9 fused iters
  kCcol<<<dim3(8, 4), 512, 0, stream>>>(Km, ru, rvpA);
  for (int it = 0; it < 9; ++it) {
    const float* src = (it & 1) ? rvpB : rvpA;
    float* dst = (it & 1) ? rvpA : rvpB;
    kCrc<<<dim3(8, 4), 512, 0, stream>>>(Km, src, dst, ru);
  }
  kAdj<<<dim3(8, 4), 512, 0, stream>>>(Km, ru, rvpB, out + 1048576);
  // GAT layer 0
  kG1<<<dim3(64, 4), 256, 0, stream>>>(X, Wg, xw);
  kG1b<<<dim3(512, 4), 128, 0, stream>>>(xw, as_, ad_, ssT, sdT);
  kG2t<<<dim3(64, 4, 4), 512, 0, stream>>>(xw, ssT, sdT, partial);
  kRed<<<256, 256, 0, stream>>>(partial, bg, x1);
  // GAT layer 1
  kG1<<<dim3(64, 4), 256, 0, stream>>>(x1, Wg + 65536, xw);
  kG1b<<<dim3(512, 4), 128, 0, stream>>>(xw, as_ + 512, ad_ + 512, ssT, sdT);
  kG2t<<<dim3(64, 4, 4), 512, 0, stream>>>(xw, ssT, sdT, partial);
  kRed<<<256, 256, 0, stream>>>(partial, bg + 128, x2);
  // final adjacency
  kF<<<dim3(16, 16, 4), 256, 0, stream>>>(x2, out);
}